// Round 4
// baseline (1186.457 us; speedup 1.0000x reference)
//
#include <hip/hip_runtime.h>

// ---------------------------------------------------------------------------
// Attention_1752346656894: 3D-window attention w/ dynamic position bias.
// Inputs: fp32 containers (proven rounds 2/3). Output: fp32 (round-3 absmax
// 0.0462 == predicted signature of bf16-written/fp32-read buffer). Internal
// compute: bf16 MFMA with fp32 accumulation.
// ---------------------------------------------------------------------------

typedef __bf16 bf16;
typedef __bf16 bf16x8 __attribute__((ext_vector_type(8)));
typedef float  f32x4  __attribute__((ext_vector_type(4)));

#define DIMC   384
#define HEADS  12
#define HD     32
#define NTOK   512
#define NWIN   64
#define LTAB   3375      // 15^3
#define PD     24
#define SM_SCALE 0.17677669529663687f   // 32^-0.5

// workspace layout (bytes) — total need 102,236,160
#define OFF_WQT  0ll           // qkv_w^T [1152][384] bf16  (884,736 B)
#define OFF_WPT  884736ll      // proj_w^T [384][384] bf16  (294,912 B)
#define OFF_POS  1179648ll     // fp32 [3375][12]           (162,000 B used)
#define OFF_Q    1572864ll     // bf16 [64*12][512][32]     (25,165,824 B)
#define OFF_K    26738688ll
#define OFF_V    51904512ll
#define OFF_AT   77070336ll    // bf16 [64][512][384]
#define WS_NEED  102236160ull

// ---------------------------------------------------------------------------
__global__ __launch_bounds__(256) void transpose_kernel(
    const float* __restrict__ src, bf16* __restrict__ dst, int K, int N)
{
    // src [K][N] fp32 -> dst [N][K] bf16
    int idx = blockIdx.x * 256 + threadIdx.x;
    if (idx >= K * N) return;
    int n = idx / K, k = idx - n * K;
    dst[idx] = (bf16)src[(size_t)k * N + n];
}

// ---------------------------------------------------------------------------
__device__ inline void ln_relu24(const float* x, const float* __restrict__ g,
                                 const float* __restrict__ b, float* y)
{
    float mean = 0.f;
#pragma unroll
    for (int j = 0; j < PD; j++) mean += x[j];
    mean *= (1.f / PD);
    float var = 0.f;
#pragma unroll
    for (int j = 0; j < PD; j++) { float d = x[j] - mean; var += d * d; }
    var *= (1.f / PD);
    float inv = rsqrtf(var + 1e-5f);
#pragma unroll
    for (int j = 0; j < PD; j++) {
        float t = (x[j] - mean) * inv * g[j] + b[j];
        y[j] = t > 0.f ? t : 0.f;
    }
}

__global__ __launch_bounds__(256) void pos_mlp_kernel(
    const float* __restrict__ pw,  const float* __restrict__ pb,
    const float* __restrict__ g1,  const float* __restrict__ b1,
    const float* __restrict__ w1,  const float* __restrict__ bb1,
    const float* __restrict__ g2,  const float* __restrict__ b2,
    const float* __restrict__ w2,  const float* __restrict__ bb2,
    const float* __restrict__ g3,  const float* __restrict__ b3,
    const float* __restrict__ w3,  const float* __restrict__ bb3,
    float* __restrict__ pos_out)
{
    int l = blockIdx.x * 256 + threadIdx.x;
    if (l >= LTAB) return;
    int ih = l / 225, iw = (l / 15) % 15, id = l % 15;
    float c0 = (float)(ih - 7), c1 = (float)(iw - 7), c2 = (float)(id - 7);
    float x[PD], y[PD];
#pragma unroll
    for (int j = 0; j < PD; j++)
        x[j] = c0 * pw[j] + c1 * pw[PD + j] + c2 * pw[2 * PD + j] + pb[j];
    ln_relu24(x, g1, b1, y);
#pragma unroll
    for (int j = 0; j < PD; j++) {
        float a = bb1[j];
#pragma unroll
        for (int i = 0; i < PD; i++) a += y[i] * w1[i * PD + j];
        x[j] = a;
    }
    ln_relu24(x, g2, b2, y);
#pragma unroll
    for (int j = 0; j < PD; j++) {
        float a = bb2[j];
#pragma unroll
        for (int i = 0; i < PD; i++) a += y[i] * w2[i * PD + j];
        x[j] = a;
    }
    ln_relu24(x, g3, b3, y);
#pragma unroll
    for (int hh = 0; hh < HEADS; hh++) {
        float a = bb3[hh];
#pragma unroll
        for (int i = 0; i < PD; i++) a += y[i] * w3[i * HEADS + hh];
        pos_out[l * HEADS + hh] = a;
    }
}

// ---------------------------------------------------------------------------
// GEMM: C[M][N] = A[M][K] @ Bt[N][K]^T + bias. 128x128 tile, BK=64.
// MODE 0: A = fp32 x, scatter bf16 into Q/K/V [b][h][n][d].
// MODE 1: A = bf16 internal, write fp32 row-major to Of.
template <int MODE>
__global__ __launch_bounds__(256) void gemm_bt(
    const void* __restrict__ Av, const bf16* __restrict__ Bt,
    const float* __restrict__ bias,
    bf16* __restrict__ O0, bf16* __restrict__ O1, bf16* __restrict__ O2,
    float* __restrict__ Of, int K, int N)
{
    __shared__ __align__(16) bf16 lA[128 * 64];
    __shared__ __align__(16) bf16 lB[128 * 64];
    const int row0 = blockIdx.x * 128;
    const int col0 = blockIdx.y * 128;
    const int tid  = threadIdx.x;
    const int lane = tid & 63;
    const int wave = tid >> 6;
    const int r0   = (wave >> 1) * 64;
    const int c0   = (wave & 1) * 64;
    const int lrow = lane & 15;
    const int lch  = lane >> 4;

    f32x4 acc[4][4];
    const f32x4 zero4 = {0.f, 0.f, 0.f, 0.f};
#pragma unroll
    for (int i = 0; i < 4; i++)
#pragma unroll
        for (int j = 0; j < 4; j++) acc[i][j] = zero4;

    for (int kt = 0; kt < K; kt += 64) {
        __syncthreads();
#pragma unroll
        for (int it = 0; it < 4; it++) {
            const int c  = tid + it * 256;
            const int rr = c >> 3;
            const int cc = (c & 7) * 8;
            const size_t aoff = (size_t)(row0 + rr) * K + kt + cc;
            if (MODE == 0) {
                const float* Af = (const float*)Av + aoff;
                float4 f0 = *(const float4*)(Af);
                float4 f1 = *(const float4*)(Af + 4);
                bf16x8 v;
                v[0] = (bf16)f0.x; v[1] = (bf16)f0.y; v[2] = (bf16)f0.z; v[3] = (bf16)f0.w;
                v[4] = (bf16)f1.x; v[5] = (bf16)f1.y; v[6] = (bf16)f1.z; v[7] = (bf16)f1.w;
                *(bf16x8*)(lA + c * 8) = v;
            } else {
                *(uint4*)(lA + c * 8) = *(const uint4*)((const bf16*)Av + aoff);
            }
            *(uint4*)(lB + c * 8) = *(const uint4*)(Bt + (size_t)(col0 + rr) * K + kt + cc);
        }
        __syncthreads();
#pragma unroll
        for (int kk = 0; kk < 64; kk += 32) {
            bf16x8 af[4], bfr[4];
#pragma unroll
            for (int i = 0; i < 4; i++)
                af[i] = *(const bf16x8*)(lA + (r0 + i * 16 + lrow) * 64 + kk + lch * 8);
#pragma unroll
            for (int j = 0; j < 4; j++)
                bfr[j] = *(const bf16x8*)(lB + (c0 + j * 16 + lrow) * 64 + kk + lch * 8);
#pragma unroll
            for (int i = 0; i < 4; i++)
#pragma unroll
                for (int j = 0; j < 4; j++)
                    acc[i][j] = __builtin_amdgcn_mfma_f32_16x16x32_bf16(af[i], bfr[j], acc[i][j], 0, 0, 0);
        }
    }

#pragma unroll
    for (int i = 0; i < 4; i++) {
#pragma unroll
        for (int j = 0; j < 4; j++) {
#pragma unroll
            for (int r = 0; r < 4; r++) {
                const int mrow = row0 + r0 + i * 16 + lch * 4 + r;   // C row = (lane>>4)*4+reg
                const int ncol = col0 + c0 + j * 16 + lrow;          // C col = lane&15
                const float v = acc[i][j][r] + bias[ncol];
                if (MODE == 0) {
                    const int t    = ncol >= 768 ? 2 : (ncol >= 384 ? 1 : 0);
                    const int rem2 = ncol - t * 384;
                    const int hh   = rem2 >> 5;
                    const int dd   = rem2 & 31;
                    const int bwin = mrow >> 9;
                    const int n    = mrow & 511;
                    bf16* dst = (t == 0) ? O0 : ((t == 1) ? O1 : O2);
                    dst[(size_t)((bwin * HEADS + hh) * NTOK + n) * HD + dd] = (bf16)v;
                } else {
                    Of[(size_t)mrow * N + ncol] = v;   // fp32 output
                }
            }
        }
    }
}

// ---------------------------------------------------------------------------
// Flash attention: block = (head, window, q-tile of 128). 4 waves x 32 q rows.
__global__ __launch_bounds__(256) void attn_kernel(
    const bf16* __restrict__ Qg, const bf16* __restrict__ Kg,
    const bf16* __restrict__ Vg, const float* __restrict__ posw,
    const float* __restrict__ maskg, bf16* __restrict__ Og)
{
    __shared__ __align__(16) bf16 lVt[32 * 136];      // V^T tile
    __shared__ __align__(16) bf16 lP[4 * 32 * 136];   // per-wave P regions

    const int idx = blockIdx.x;
    const int h   = idx >> 8;       // same-h blocks contiguous -> pos L2 reuse
    const int rem = idx & 255;
    const int b   = rem >> 2;
    const int qt  = rem & 3;
    const int g   = b & 7;          // mask group
    const int tid = threadIdx.x;
    const int lane = tid & 63;
    const int wave = tid >> 6;
    const int lrow = lane & 15;
    const int lch  = lane >> 4;

    const bf16* Qp = Qg + (size_t)(b * HEADS + h) * NTOK * HD;
    const bf16* Kp = Kg + (size_t)(b * HEADS + h) * NTOK * HD;
    const bf16* Vp = Vg + (size_t)(b * HEADS + h) * NTOK * HD;
    const float* Mp = maskg + (size_t)g * NTOK * NTOK;

    const int qbase = qt * 128 + wave * 32;

    // Q fragments (A-layout: row=lane&15, k=(lane>>4)*8..+7) — 16B coalesced
    bf16x8 qf[2];
#pragma unroll
    for (int rt = 0; rt < 2; rt++)
        qf[rt] = *(const bf16x8*)(Qp + (qbase + rt * 16 + lrow) * HD + lch * 8);

    float m_i[2][4], l_i[2][4];
    f32x4 oacc[2][2];
    const f32x4 zero4 = {0.f, 0.f, 0.f, 0.f};
#pragma unroll
    for (int rt = 0; rt < 2; rt++) {
#pragma unroll
        for (int r = 0; r < 4; r++) { m_i[rt][r] = -30.0f; l_i[rt][r] = 0.f; }
        oacc[rt][0] = zero4;
        oacc[rt][1] = zero4;
    }

    bf16* myP = lP + wave * (32 * 136);

    for (int kt = 0; kt < 4; kt++) {
        __syncthreads();             // all waves done reading previous lVt
        {
            // stage V^T: thread covers one (row, 16-col half)
            const int vr = tid >> 1;
            const int vc = (tid & 1) * 16;
            const bf16* vsrc = Vp + (kt * 128 + vr) * HD + vc;
            bf16x8 v0 = *(const bf16x8*)(vsrc);
            bf16x8 v1 = *(const bf16x8*)(vsrc + 8);
#pragma unroll
            for (int c = 0; c < 8; c++) lVt[(vc + c) * 136 + vr] = v0[c];
#pragma unroll
            for (int c = 0; c < 8; c++) lVt[(vc + 8 + c) * 136 + vr] = v1[c];
        }
        __syncthreads();

        // S = Q @ K^T  (K fragment loads identical pattern to A: B^T trick)
        f32x4 sf[2][8];
#pragma unroll
        for (int ct = 0; ct < 8; ct++) {
            bf16x8 kf = *(const bf16x8*)(Kp + (kt * 128 + ct * 16 + lrow) * HD + lch * 8);
#pragma unroll
            for (int rt = 0; rt < 2; rt++)
                sf[rt][ct] = __builtin_amdgcn_mfma_f32_16x16x32_bf16(qf[rt], kf, zero4, 0, 0, 0);
        }

        // scale + pos-bias gather + mask (C-layout: row=(lane>>4)*4+reg, col=lane&15)
        const int mb = kt * 128 + lrow;
#pragma unroll
        for (int rt = 0; rt < 2; rt++) {
#pragma unroll
            for (int r = 0; r < 4; r++) {
                const int row = qbase + rt * 16 + lch * 4 + r;
                const int nh = row >> 6, nw = (row >> 3) & 7, nd = row & 7;
                const float* mp = Mp + (size_t)row * NTOK + mb;
#pragma unroll
                for (int ct = 0; ct < 8; ct++) {
                    const int m  = mb + ct * 16;
                    const int dh = nh - (m >> 6) + 7;
                    const int dw = nw - ((m >> 3) & 7) + 7;
                    const int dd = nd - (m & 7) + 7;
                    const float pb = posw[(dh * 225 + dw * 15 + dd) * HEADS + h];
                    sf[rt][ct][r] = sf[rt][ct][r] * SM_SCALE + pb + mp[ct * 16];
                }
            }
        }

        // online softmax; rows of a tile live across lanes differing in low 4 bits
#pragma unroll
        for (int rt = 0; rt < 2; rt++) {
#pragma unroll
            for (int r = 0; r < 4; r++) {
                float mx = sf[rt][0][r];
#pragma unroll
                for (int ct = 1; ct < 8; ct++) mx = fmaxf(mx, sf[rt][ct][r]);
                mx = fmaxf(mx, __shfl_xor(mx, 1));
                mx = fmaxf(mx, __shfl_xor(mx, 2));
                mx = fmaxf(mx, __shfl_xor(mx, 4));
                mx = fmaxf(mx, __shfl_xor(mx, 8));
                const float mold  = m_i[rt][r];
                const float mnew  = fmaxf(mold, mx);
                const float alpha = __expf(mold - mnew);
                m_i[rt][r] = mnew;
                float ls = 0.f;
                const int prow = (rt * 16 + lch * 4 + r) * 136 + lrow;
#pragma unroll
                for (int ct = 0; ct < 8; ct++) {
                    float p = __expf(sf[rt][ct][r] - mnew);
                    ls += p;
                    myP[prow + ct * 16] = (bf16)p;   // C-layout -> LDS
                }
                ls += __shfl_xor(ls, 1);
                ls += __shfl_xor(ls, 2);
                ls += __shfl_xor(ls, 4);
                ls += __shfl_xor(ls, 8);
                l_i[rt][r] = l_i[rt][r] * alpha + ls;
                oacc[rt][0][r] *= alpha;
                oacc[rt][1][r] *= alpha;
            }
        }

        __syncthreads();   // drain all P LDS writes before A-layout re-read

        // O += P @ V   (P re-read in A-layout from wave-private LDS)
#pragma unroll
        for (int kk = 0; kk < 4; kk++) {
            bf16x8 bv[2];
#pragma unroll
            for (int ct = 0; ct < 2; ct++)
                bv[ct] = *(const bf16x8*)(lVt + (ct * 16 + lrow) * 136 + kk * 32 + lch * 8);
#pragma unroll
            for (int rt = 0; rt < 2; rt++) {
                bf16x8 ap = *(const bf16x8*)(myP + (rt * 16 + lrow) * 136 + kk * 32 + lch * 8);
#pragma unroll
                for (int ct = 0; ct < 2; ct++)
                    oacc[rt][ct] = __builtin_amdgcn_mfma_f32_16x16x32_bf16(ap, bv[ct], oacc[rt][ct], 0, 0, 0);
            }
        }
    }

    // epilogue: normalize, store to [b][n][h*32+c]
#pragma unroll
    for (int rt = 0; rt < 2; rt++) {
#pragma unroll
        for (int r = 0; r < 4; r++) {
            const int n = qbase + rt * 16 + lch * 4 + r;
            const float inv = 1.f / fmaxf(l_i[rt][r], 1e-20f);
            bf16* orow = Og + (size_t)(b * NTOK + n) * DIMC + h * HD;
#pragma unroll
            for (int ct = 0; ct < 2; ct++)
                orow[ct * 16 + lrow] = (bf16)(oacc[rt][ct][r] * inv);
        }
    }
}

// ---------------------------------------------------------------------------
extern "C" void kernel_launch(void* const* d_in, const int* in_sizes, int n_in,
                              void* d_out, int out_size, void* d_ws, size_t ws_size,
                              hipStream_t stream)
{
    if (ws_size < WS_NEED) return;   // diagnostic guard (round 3 proved ws OK)

    const float* x      = (const float*)d_in[0];
    // d_in[1..3] = H, W, D (int, always 8)
    const float* maskp  = (const float*)d_in[4];
    const float* qkv_w  = (const float*)d_in[5];
    const float* qkv_b  = (const float*)d_in[6];
    const float* proj_w = (const float*)d_in[7];
    const float* proj_b = (const float*)d_in[8];

    char* ws = (char*)d_ws;
    bf16*  wsWqT  = (bf16*)(ws + OFF_WQT);
    bf16*  wsWpT  = (bf16*)(ws + OFF_WPT);
    float* wsPos  = (float*)(ws + OFF_POS);
    bf16*  wsQ    = (bf16*)(ws + OFF_Q);
    bf16*  wsK    = (bf16*)(ws + OFF_K);
    bf16*  wsV    = (bf16*)(ws + OFF_V);
    bf16*  wsAttn = (bf16*)(ws + OFF_AT);

    transpose_kernel<<<(384 * 1152 + 255) / 256, 256, 0, stream>>>(qkv_w, wsWqT, 384, 1152);
    transpose_kernel<<<(384 * 384 + 255) / 256, 256, 0, stream>>>(proj_w, wsWpT, 384, 384);
    pos_mlp_kernel<<<(LTAB + 255) / 256, 256, 0, stream>>>(
        (const float*)d_in[9],  (const float*)d_in[10], (const float*)d_in[11],
        (const float*)d_in[12], (const float*)d_in[13], (const float*)d_in[14],
        (const float*)d_in[15], (const float*)d_in[16], (const float*)d_in[17],
        (const float*)d_in[18], (const float*)d_in[19], (const float*)d_in[20],
        (const float*)d_in[21], (const float*)d_in[22], wsPos);

    // QKV: [32768 x 384] @ [384 x 1152] -> scatter Q/K/V
    gemm_bt<0><<<dim3(256, 9), 256, 0, stream>>>(x, wsWqT, qkv_b, wsQ, wsK, wsV,
                                                 nullptr, 384, 1152);

    attn_kernel<<<HEADS * NWIN * 4, 256, 0, stream>>>(wsQ, wsK, wsV, wsPos, maskp, wsAttn);

    // proj: [32768 x 384] @ [384 x 384] -> d_out (fp32)
    gemm_bt<1><<<dim3(256, 3), 256, 0, stream>>>(wsAttn, wsWpT, proj_b,
                                                 nullptr, nullptr, nullptr,
                                                 (float*)d_out, 384, 384);
}

// Round 5
// 557.209 us; speedup vs baseline: 2.1293x; 2.1293x over previous
//
#include <hip/hip_runtime.h>

// ---------------------------------------------------------------------------
// Attention_1752346656894: 3D-window attention w/ dynamic position bias.
// Inputs fp32, output fp32, internal bf16 MFMA w/ fp32 accum.
// R5: remove attn scalar-gather stalls (R4: MfmaUtil 1.6%, VALUBusy 14%,
// occupancy 24% -> latency-bound on 512 scalar VMEM gathers/lane).
// Host picks BIG (b64 bias/mask tables) vs SMALL (LDS posT) by ws_size.
// ---------------------------------------------------------------------------

typedef __bf16 bf16;
typedef __bf16 bf16x4 __attribute__((ext_vector_type(4)));
typedef __bf16 bf16x8 __attribute__((ext_vector_type(8)));
typedef float  f32x4  __attribute__((ext_vector_type(4)));

#define DIMC   384
#define HEADS  12
#define HD     32
#define NTOK   512
#define NWIN   64
#define LTAB   3375      // 15^3
#define LPAD   3392      // padded to 16B multiple (bf16)
#define PD     24
#define SM_SCALE 0.17677669529663687f   // 32^-0.5

#define SZ_WQT  884736ll
#define SZ_WPT  294912ll
#define SZ_POST 81408ll        // bf16 [12][3392]
#define SZ_B2   6291456ll      // bf16 [12][512][512]
#define SZ_MT   4194304ll      // bf16 [8][512][512]
#define SZ_QKV  25165824ll
#define WS_SMALL 102236160ull  // proven in round 4
#define WS_BIG   112410112ull

// ---------------------------------------------------------------------------
__global__ __launch_bounds__(256) void transpose_kernel(
    const float* __restrict__ src, bf16* __restrict__ dst, int K, int N)
{
    int idx = blockIdx.x * 256 + threadIdx.x;
    if (idx >= K * N) return;
    int n = idx / K, k = idx - n * K;
    dst[idx] = (bf16)src[(size_t)k * N + n];
}

// ---------------------------------------------------------------------------
__device__ inline void ln_relu24(const float* x, const float* __restrict__ g,
                                 const float* __restrict__ b, float* y)
{
    float mean = 0.f;
#pragma unroll
    for (int j = 0; j < PD; j++) mean += x[j];
    mean *= (1.f / PD);
    float var = 0.f;
#pragma unroll
    for (int j = 0; j < PD; j++) { float d = x[j] - mean; var += d * d; }
    var *= (1.f / PD);
    float inv = rsqrtf(var + 1e-5f);
#pragma unroll
    for (int j = 0; j < PD; j++) {
        float t = (x[j] - mean) * inv * g[j] + b[j];
        y[j] = t > 0.f ? t : 0.f;
    }
}

__global__ __launch_bounds__(256) void pos_mlp_kernel(
    const float* __restrict__ pw,  const float* __restrict__ pb,
    const float* __restrict__ g1,  const float* __restrict__ b1,
    const float* __restrict__ w1,  const float* __restrict__ bb1,
    const float* __restrict__ g2,  const float* __restrict__ b2,
    const float* __restrict__ w2,  const float* __restrict__ bb2,
    const float* __restrict__ g3,  const float* __restrict__ b3,
    const float* __restrict__ w3,  const float* __restrict__ bb3,
    bf16* __restrict__ posTg)      // [12][LPAD] bf16, transposed
{
    int l = blockIdx.x * 256 + threadIdx.x;
    if (l >= LTAB) return;
    int ih = l / 225, iw = (l / 15) % 15, id = l % 15;
    float c0 = (float)(ih - 7), c1 = (float)(iw - 7), c2 = (float)(id - 7);
    float x[PD], y[PD];
#pragma unroll
    for (int j = 0; j < PD; j++)
        x[j] = c0 * pw[j] + c1 * pw[PD + j] + c2 * pw[2 * PD + j] + pb[j];
    ln_relu24(x, g1, b1, y);
#pragma unroll
    for (int j = 0; j < PD; j++) {
        float a = bb1[j];
#pragma unroll
        for (int i = 0; i < PD; i++) a += y[i] * w1[i * PD + j];
        x[j] = a;
    }
    ln_relu24(x, g2, b2, y);
#pragma unroll
    for (int j = 0; j < PD; j++) {
        float a = bb2[j];
#pragma unroll
        for (int i = 0; i < PD; i++) a += y[i] * w2[i * PD + j];
        x[j] = a;
    }
    ln_relu24(x, g3, b3, y);
#pragma unroll
    for (int hh = 0; hh < HEADS; hh++) {
        float a = bb3[hh];
#pragma unroll
        for (int i = 0; i < PD; i++) a += y[i] * w3[i * HEADS + hh];
        posTg[hh * LPAD + l] = (bf16)a;
    }
}

// ---------------------------------------------------------------------------
// bias2[h][m][n] = pos-bias for (q-row n, k-col m). Coalesced writes along n.
__global__ __launch_bounds__(256) void bias2_build_kernel(
    const bf16* __restrict__ posTg, bf16* __restrict__ bias2)
{
    int idx = blockIdx.x * 256 + threadIdx.x;   // 12*512*512 exact grid
    int h = idx >> 18;
    int m = (idx >> 9) & 511;
    int n = idx & 511;
    int dh = (n >> 6) - (m >> 6) + 7;
    int dw = ((n >> 3) & 7) - ((m >> 3) & 7) + 7;
    int dd = (n & 7) - (m & 7) + 7;
    bias2[idx] = posTg[h * LPAD + dh * 225 + dw * 15 + dd];
}

// ---------------------------------------------------------------------------
// mt[g][m][n] = (bf16)mask[g][n][m]  (LDS-tiled transpose, 64x64 tiles)
__global__ __launch_bounds__(256) void mt_build_kernel(
    const float* __restrict__ mask, bf16* __restrict__ mt)
{
    __shared__ float tile[64][65];
    const int bx = blockIdx.x;           // g*64 + tm*8 + tn
    const int g  = bx >> 6;
    const int m0 = ((bx >> 3) & 7) * 64;
    const int n0 = (bx & 7) * 64;
    const int tid = threadIdx.x;
#pragma unroll
    for (int k = 0; k < 16; k++) {
        int lin = tid + k * 256;
        int r = lin >> 6, c = lin & 63;
        tile[r][c] = mask[((size_t)g * NTOK + n0 + r) * NTOK + m0 + c];
    }
    __syncthreads();
#pragma unroll
    for (int k = 0; k < 16; k++) {
        int lin = tid + k * 256;
        int mr = lin >> 6, nc = lin & 63;
        mt[((size_t)g * NTOK + m0 + mr) * NTOK + n0 + nc] = (bf16)tile[nc][mr];
    }
}

// ---------------------------------------------------------------------------
// GEMM: C[M][N] = A[M][K] @ Bt[N][K]^T + bias. 128x128 tile, BK=64.
template <int MODE>
__global__ __launch_bounds__(256) void gemm_bt(
    const void* __restrict__ Av, const bf16* __restrict__ Bt,
    const float* __restrict__ bias,
    bf16* __restrict__ O0, bf16* __restrict__ O1, bf16* __restrict__ O2,
    float* __restrict__ Of, int K, int N)
{
    __shared__ __align__(16) bf16 lA[128 * 64];
    __shared__ __align__(16) bf16 lB[128 * 64];
    const int row0 = blockIdx.x * 128;
    const int col0 = blockIdx.y * 128;
    const int tid  = threadIdx.x;
    const int lane = tid & 63;
    const int wave = tid >> 6;
    const int r0   = (wave >> 1) * 64;
    const int c0   = (wave & 1) * 64;
    const int lrow = lane & 15;
    const int lch  = lane >> 4;

    f32x4 acc[4][4];
    const f32x4 zero4 = {0.f, 0.f, 0.f, 0.f};
#pragma unroll
    for (int i = 0; i < 4; i++)
#pragma unroll
        for (int j = 0; j < 4; j++) acc[i][j] = zero4;

    for (int kt = 0; kt < K; kt += 64) {
        __syncthreads();
#pragma unroll
        for (int it = 0; it < 4; it++) {
            const int c  = tid + it * 256;
            const int rr = c >> 3;
            const int cc = (c & 7) * 8;
            const size_t aoff = (size_t)(row0 + rr) * K + kt + cc;
            if (MODE == 0) {
                const float* Af = (const float*)Av + aoff;
                float4 f0 = *(const float4*)(Af);
                float4 f1 = *(const float4*)(Af + 4);
                bf16x8 v;
                v[0] = (bf16)f0.x; v[1] = (bf16)f0.y; v[2] = (bf16)f0.z; v[3] = (bf16)f0.w;
                v[4] = (bf16)f1.x; v[5] = (bf16)f1.y; v[6] = (bf16)f1.z; v[7] = (bf16)f1.w;
                *(bf16x8*)(lA + c * 8) = v;
            } else {
                *(uint4*)(lA + c * 8) = *(const uint4*)((const bf16*)Av + aoff);
            }
            *(uint4*)(lB + c * 8) = *(const uint4*)(Bt + (size_t)(col0 + rr) * K + kt + cc);
        }
        __syncthreads();
#pragma unroll
        for (int kk = 0; kk < 64; kk += 32) {
            bf16x8 af[4], bfr[4];
#pragma unroll
            for (int i = 0; i < 4; i++)
                af[i] = *(const bf16x8*)(lA + (r0 + i * 16 + lrow) * 64 + kk + lch * 8);
#pragma unroll
            for (int j = 0; j < 4; j++)
                bfr[j] = *(const bf16x8*)(lB + (c0 + j * 16 + lrow) * 64 + kk + lch * 8);
#pragma unroll
            for (int i = 0; i < 4; i++)
#pragma unroll
                for (int j = 0; j < 4; j++)
                    acc[i][j] = __builtin_amdgcn_mfma_f32_16x16x32_bf16(af[i], bfr[j], acc[i][j], 0, 0, 0);
        }
    }

#pragma unroll
    for (int i = 0; i < 4; i++) {
#pragma unroll
        for (int j = 0; j < 4; j++) {
#pragma unroll
            for (int r = 0; r < 4; r++) {
                const int mrow = row0 + r0 + i * 16 + lch * 4 + r;
                const int ncol = col0 + c0 + j * 16 + lrow;
                const float v = acc[i][j][r] + bias[ncol];
                if (MODE == 0) {
                    const int t    = ncol >= 768 ? 2 : (ncol >= 384 ? 1 : 0);
                    const int rem2 = ncol - t * 384;
                    const int hh   = rem2 >> 5;
                    const int dd   = rem2 & 31;
                    const int bwin = mrow >> 9;
                    const int n    = mrow & 511;
                    bf16* dst = (t == 0) ? O0 : ((t == 1) ? O1 : O2);
                    dst[(size_t)((bwin * HEADS + hh) * NTOK + n) * HD + dd] = (bf16)v;
                } else {
                    Of[(size_t)mrow * N + ncol] = v;
                }
            }
        }
    }
}

// ---------------------------------------------------------------------------
// Flash attention. BIG=1: bias/mask via b64 table loads (bias2[h][m][n],
// mt[g][m][n]); BIG=0: posT slice in LDS + scalar fp32 mask loads.
template <int BIG>
__global__ __launch_bounds__(256) void attn_kernel(
    const bf16* __restrict__ Qg, const bf16* __restrict__ Kg,
    const bf16* __restrict__ Vg, const bf16* __restrict__ posTg,
    const float* __restrict__ maskg, const bf16* __restrict__ bias2,
    const bf16* __restrict__ mt, bf16* __restrict__ Og)
{
    __shared__ __align__(16) bf16 lVt[32 * 136];      // V^T tile
    __shared__ __align__(16) bf16 lP[4 * 32 * 136];   // per-wave P regions
    __shared__ __align__(16) bf16 lPos[BIG ? 16 : LPAD];

    const int idx = blockIdx.x;
    const int h   = idx >> 8;
    const int rem = idx & 255;
    const int b   = rem >> 2;
    const int qt  = rem & 3;
    const int g   = b & 7;
    const int tid = threadIdx.x;
    const int lane = tid & 63;
    const int wave = tid >> 6;
    const int lrow = lane & 15;
    const int lch  = lane >> 4;

    if (!BIG) {   // stage this head's posT slice (6784 B) into LDS
        const uint4* src = (const uint4*)(posTg + h * LPAD);
        for (int i = tid; i < LPAD * 2 / 16; i += 256)
            ((uint4*)lPos)[i] = src[i];
    }

    const bf16* Qp = Qg + (size_t)(b * HEADS + h) * NTOK * HD;
    const bf16* Kp = Kg + (size_t)(b * HEADS + h) * NTOK * HD;
    const bf16* Vp = Vg + (size_t)(b * HEADS + h) * NTOK * HD;
    const float* Mp = maskg + (size_t)g * NTOK * NTOK;
    const bf16* B2p = bias2 + (size_t)h * NTOK * NTOK;
    const bf16* Mtp = mt + (size_t)g * NTOK * NTOK;

    const int qbase = qt * 128 + wave * 32;

    bf16x8 qf[2];
#pragma unroll
    for (int rt = 0; rt < 2; rt++)
        qf[rt] = *(const bf16x8*)(Qp + (qbase + rt * 16 + lrow) * HD + lch * 8);

    float m_i[2][4], l_i[2][4];
    f32x4 oacc[2][2];
    const f32x4 zero4 = {0.f, 0.f, 0.f, 0.f};
#pragma unroll
    for (int rt = 0; rt < 2; rt++) {
#pragma unroll
        for (int r = 0; r < 4; r++) { m_i[rt][r] = -30.0f; l_i[rt][r] = 0.f; }
        oacc[rt][0] = zero4;
        oacc[rt][1] = zero4;
    }

    bf16* myP = lP + wave * (32 * 136);

    for (int kt = 0; kt < 4; kt++) {
        __syncthreads();
        {
            const int vr = tid >> 1;
            const int vc = (tid & 1) * 16;
            const bf16* vsrc = Vp + (kt * 128 + vr) * HD + vc;
            bf16x8 v0 = *(const bf16x8*)(vsrc);
            bf16x8 v1 = *(const bf16x8*)(vsrc + 8);
#pragma unroll
            for (int c = 0; c < 8; c++) lVt[(vc + c) * 136 + vr] = v0[c];
#pragma unroll
            for (int c = 0; c < 8; c++) lVt[(vc + 8 + c) * 136 + vr] = v1[c];
        }
        __syncthreads();

        // S = Q @ K^T
        f32x4 sf[2][8];
#pragma unroll
        for (int ct = 0; ct < 8; ct++) {
            bf16x8 kf = *(const bf16x8*)(Kp + (kt * 128 + ct * 16 + lrow) * HD + lch * 8);
#pragma unroll
            for (int rt = 0; rt < 2; rt++)
                sf[rt][ct] = __builtin_amdgcn_mfma_f32_16x16x32_bf16(qf[rt], kf, zero4, 0, 0, 0);
        }

        // scale + bias + mask
        if (BIG) {
            const int n_base = qbase + lch * 4;           // mult of 4 -> 8B aligned
#pragma unroll
            for (int ct = 0; ct < 8; ct++) {
                const int m = kt * 128 + ct * 16 + lrow;
                const size_t tb = (size_t)m * NTOK + n_base;
#pragma unroll
                for (int rt = 0; rt < 2; rt++) {
                    bf16x4 bv = *(const bf16x4*)(B2p + tb + rt * 16);
                    bf16x4 mv = *(const bf16x4*)(Mtp + tb + rt * 16);
#pragma unroll
                    for (int r = 0; r < 4; r++)
                        sf[rt][ct][r] = sf[rt][ct][r] * SM_SCALE + (float)bv[r] + (float)mv[r];
                }
            }
        } else {
            const int mb = kt * 128 + lrow;
#pragma unroll
            for (int rt = 0; rt < 2; rt++) {
#pragma unroll
                for (int r = 0; r < 4; r++) {
                    const int row = qbase + rt * 16 + lch * 4 + r;
                    const int nh = row >> 6, nw = (row >> 3) & 7, nd = row & 7;
                    const float* mp = Mp + (size_t)row * NTOK + mb;
#pragma unroll
                    for (int ct = 0; ct < 8; ct++) {
                        const int m  = mb + ct * 16;
                        const int rpi = (nh - (m >> 6) + 7) * 225
                                      + (nw - ((m >> 3) & 7) + 7) * 15
                                      + (nd - (m & 7) + 7);
                        sf[rt][ct][r] = sf[rt][ct][r] * SM_SCALE
                                      + (float)lPos[rpi] + mp[ct * 16];
                    }
                }
            }
        }

        // online softmax
#pragma unroll
        for (int rt = 0; rt < 2; rt++) {
#pragma unroll
            for (int r = 0; r < 4; r++) {
                float mx = sf[rt][0][r];
#pragma unroll
                for (int ct = 1; ct < 8; ct++) mx = fmaxf(mx, sf[rt][ct][r]);
                mx = fmaxf(mx, __shfl_xor(mx, 1));
                mx = fmaxf(mx, __shfl_xor(mx, 2));
                mx = fmaxf(mx, __shfl_xor(mx, 4));
                mx = fmaxf(mx, __shfl_xor(mx, 8));
                const float mold  = m_i[rt][r];
                const float mnew  = fmaxf(mold, mx);
                const float alpha = __expf(mold - mnew);
                m_i[rt][r] = mnew;
                float ls = 0.f;
                const int prow = (rt * 16 + lch * 4 + r) * 136 + lrow;
#pragma unroll
                for (int ct = 0; ct < 8; ct++) {
                    float p = __expf(sf[rt][ct][r] - mnew);
                    ls += p;
                    myP[prow + ct * 16] = (bf16)p;
                }
                ls += __shfl_xor(ls, 1);
                ls += __shfl_xor(ls, 2);
                ls += __shfl_xor(ls, 4);
                ls += __shfl_xor(ls, 8);
                l_i[rt][r] = l_i[rt][r] * alpha + ls;
                oacc[rt][0][r] *= alpha;
                oacc[rt][1][r] *= alpha;
            }
        }

        __syncthreads();   // drain P LDS writes before A-layout re-read

        // O += P @ V
#pragma unroll
        for (int kk = 0; kk < 4; kk++) {
            bf16x8 bv[2];
#pragma unroll
            for (int ct = 0; ct < 2; ct++)
                bv[ct] = *(const bf16x8*)(lVt + (ct * 16 + lrow) * 136 + kk * 32 + lch * 8);
#pragma unroll
            for (int rt = 0; rt < 2; rt++) {
                bf16x8 ap = *(const bf16x8*)(myP + (rt * 16 + lrow) * 136 + kk * 32 + lch * 8);
#pragma unroll
                for (int ct = 0; ct < 2; ct++)
                    oacc[rt][ct] = __builtin_amdgcn_mfma_f32_16x16x32_bf16(ap, bv[ct], oacc[rt][ct], 0, 0, 0);
            }
        }
    }

#pragma unroll
    for (int rt = 0; rt < 2; rt++) {
#pragma unroll
        for (int r = 0; r < 4; r++) {
            const int n = qbase + rt * 16 + lch * 4 + r;
            const float inv = 1.f / fmaxf(l_i[rt][r], 1e-20f);
            bf16* orow = Og + (size_t)(b * NTOK + n) * DIMC + h * HD;
#pragma unroll
            for (int ct = 0; ct < 2; ct++)
                orow[ct * 16 + lrow] = (bf16)(oacc[rt][ct][r] * inv);
        }
    }
}

// ---------------------------------------------------------------------------
extern "C" void kernel_launch(void* const* d_in, const int* in_sizes, int n_in,
                              void* d_out, int out_size, void* d_ws, size_t ws_size,
                              hipStream_t stream)
{
    if (ws_size < WS_SMALL) return;
    const bool BIG = (ws_size >= WS_BIG);

    const float* x      = (const float*)d_in[0];
    const float* maskp  = (const float*)d_in[4];
    const float* qkv_w  = (const float*)d_in[5];
    const float* qkv_b  = (const float*)d_in[6];
    const float* proj_w = (const float*)d_in[7];
    const float* proj_b = (const float*)d_in[8];

    char* ws = (char*)d_ws;
    size_t off = 0;
    bf16* wsWqT  = (bf16*)(ws + off); off += SZ_WQT;
    bf16* wsWpT  = (bf16*)(ws + off); off += SZ_WPT;
    bf16* wsPosT = (bf16*)(ws + off); off += SZ_POST;
    bf16* wsB2 = nullptr; bf16* wsMt = nullptr;
    if (BIG) {
        wsB2 = (bf16*)(ws + off); off += SZ_B2;
        wsMt = (bf16*)(ws + off); off += SZ_MT;
    } else {
        off = 1572864;   // round-4 proven layout
    }
    bf16* wsQ    = (bf16*)(ws + off); off += SZ_QKV;
    bf16* wsK    = (bf16*)(ws + off); off += SZ_QKV;
    bf16* wsV    = (bf16*)(ws + off); off += SZ_QKV;
    bf16* wsAttn = (bf16*)(ws + off);

    transpose_kernel<<<(384 * 1152 + 255) / 256, 256, 0, stream>>>(qkv_w, wsWqT, 384, 1152);
    transpose_kernel<<<(384 * 384 + 255) / 256, 256, 0, stream>>>(proj_w, wsWpT, 384, 384);
    pos_mlp_kernel<<<(LTAB + 255) / 256, 256, 0, stream>>>(
        (const float*)d_in[9],  (const float*)d_in[10], (const float*)d_in[11],
        (const float*)d_in[12], (const float*)d_in[13], (const float*)d_in[14],
        (const float*)d_in[15], (const float*)d_in[16], (const float*)d_in[17],
        (const float*)d_in[18], (const float*)d_in[19], (const float*)d_in[20],
        (const float*)d_in[21], (const float*)d_in[22], wsPosT);

    if (BIG) {
        bias2_build_kernel<<<(HEADS * NTOK * NTOK) / 256, 256, 0, stream>>>(wsPosT, wsB2);
        mt_build_kernel<<<8 * 64, 256, 0, stream>>>(maskp, wsMt);
    }

    // QKV: [32768 x 384] @ [384 x 1152] -> scatter Q/K/V
    gemm_bt<0><<<dim3(256, 9), 256, 0, stream>>>(x, wsWqT, qkv_b, wsQ, wsK, wsV,
                                                 nullptr, 384, 1152);

    if (BIG)
        attn_kernel<1><<<HEADS * NWIN * 4, 256, 0, stream>>>(
            wsQ, wsK, wsV, wsPosT, maskp, wsB2, wsMt, wsAttn);
    else
        attn_kernel<0><<<HEADS * NWIN * 4, 256, 0, stream>>>(
            wsQ, wsK, wsV, wsPosT, maskp, wsB2, wsMt, wsAttn);

    // proj: [32768 x 384] @ [384 x 384] -> d_out (fp32)
    gemm_bt<1><<<dim3(256, 3), 256, 0, stream>>>(wsAttn, wsWpT, proj_b,
                                                 nullptr, nullptr, nullptr,
                                                 (float*)d_out, 384, 384);
}

// Round 6
// 448.955 us; speedup vs baseline: 2.6427x; 1.2411x over previous
//
#include <hip/hip_runtime.h>

// ---------------------------------------------------------------------------
// Attention_1752346656894: 3D-window attention w/ dynamic position bias.
// Inputs fp32, output fp32, internal bf16 MFMA w/ fp32 accum.
// R6: barrier-free attn main loop (R5 counters: VALU 27%, Mfma 3.4%, occ 21%
// -> barrier-convoy latency). Full V^T prestage (1 barrier total), wave-
// private P in two 64-m halves (LDS 51.7KB = 3 blocks/CU), Q prescaled by
// softmax scale, mask loads skipped via runtime zero-mask flag.
// ---------------------------------------------------------------------------

typedef __bf16 bf16;
typedef __bf16 bf16x4 __attribute__((ext_vector_type(4)));
typedef __bf16 bf16x8 __attribute__((ext_vector_type(8)));
typedef float  f32x4  __attribute__((ext_vector_type(4)));

#define DIMC   384
#define HEADS  12
#define HD     32
#define NTOK   512
#define NWIN   64
#define LTAB   3375      // 15^3
#define LPAD   3392      // padded to 16B multiple (bf16)
#define PD     24
#define SM_SCALE 0.17677669529663687f   // 32^-0.5
#define VSTR   520       // lVt row stride (bf16): 512+8
#define PSTR   72        // lP row stride (bf16): 64+8

#define SZ_WQT  884736ll
#define SZ_WPT  294912ll
#define SZ_POST 81408ll        // bf16 [12][3392]
#define SZ_FLAG 256ll
#define SZ_B2   6291456ll      // bf16 [12][512][512]
#define SZ_MT   4194304ll      // bf16 [8][512][512]
#define SZ_QKV  25165824ll
#define WS_SMALL 102236160ull  // proven in round 4
#define WS_BIG   112410368ull

// ---------------------------------------------------------------------------
__global__ __launch_bounds__(256) void transpose_kernel(
    const float* __restrict__ src, bf16* __restrict__ dst, int K, int N)
{
    int idx = blockIdx.x * 256 + threadIdx.x;
    if (idx >= K * N) return;
    int n = idx / K, k = idx - n * K;
    dst[idx] = (bf16)src[(size_t)k * N + n];
}

// ---------------------------------------------------------------------------
__global__ __launch_bounds__(256) void mask_detect_kernel(
    const float* __restrict__ mask, int* __restrict__ flag)
{
    int i = blockIdx.x * 256 + threadIdx.x;   // 256 blocks x 256 thr x 32 elems
    const float* p = mask + (size_t)i * 32;
    float s = 0.f;
#pragma unroll
    for (int j = 0; j < 32; j++) s += fabsf(p[j]);
    if (!(s == 0.f)) atomicOr(flag, 1);       // catches nonzero/inf/NaN
}

// ---------------------------------------------------------------------------
__device__ inline void ln_relu24(const float* x, const float* __restrict__ g,
                                 const float* __restrict__ b, float* y)
{
    float mean = 0.f;
#pragma unroll
    for (int j = 0; j < PD; j++) mean += x[j];
    mean *= (1.f / PD);
    float var = 0.f;
#pragma unroll
    for (int j = 0; j < PD; j++) { float d = x[j] - mean; var += d * d; }
    var *= (1.f / PD);
    float inv = rsqrtf(var + 1e-5f);
#pragma unroll
    for (int j = 0; j < PD; j++) {
        float t = (x[j] - mean) * inv * g[j] + b[j];
        y[j] = t > 0.f ? t : 0.f;
    }
}

__global__ __launch_bounds__(256) void pos_mlp_kernel(
    const float* __restrict__ pw,  const float* __restrict__ pb,
    const float* __restrict__ g1,  const float* __restrict__ b1,
    const float* __restrict__ w1,  const float* __restrict__ bb1,
    const float* __restrict__ g2,  const float* __restrict__ b2,
    const float* __restrict__ w2,  const float* __restrict__ bb2,
    const float* __restrict__ g3,  const float* __restrict__ b3,
    const float* __restrict__ w3,  const float* __restrict__ bb3,
    bf16* __restrict__ posTg)      // [12][LPAD] bf16, transposed
{
    int l = blockIdx.x * 256 + threadIdx.x;
    if (l >= LTAB) return;
    int ih = l / 225, iw = (l / 15) % 15, id = l % 15;
    float c0 = (float)(ih - 7), c1 = (float)(iw - 7), c2 = (float)(id - 7);
    float x[PD], y[PD];
#pragma unroll
    for (int j = 0; j < PD; j++)
        x[j] = c0 * pw[j] + c1 * pw[PD + j] + c2 * pw[2 * PD + j] + pb[j];
    ln_relu24(x, g1, b1, y);
#pragma unroll
    for (int j = 0; j < PD; j++) {
        float a = bb1[j];
#pragma unroll
        for (int i = 0; i < PD; i++) a += y[i] * w1[i * PD + j];
        x[j] = a;
    }
    ln_relu24(x, g2, b2, y);
#pragma unroll
    for (int j = 0; j < PD; j++) {
        float a = bb2[j];
#pragma unroll
        for (int i = 0; i < PD; i++) a += y[i] * w2[i * PD + j];
        x[j] = a;
    }
    ln_relu24(x, g3, b3, y);
#pragma unroll
    for (int hh = 0; hh < HEADS; hh++) {
        float a = bb3[hh];
#pragma unroll
        for (int i = 0; i < PD; i++) a += y[i] * w3[i * HEADS + hh];
        posTg[hh * LPAD + l] = (bf16)a;
    }
}

// ---------------------------------------------------------------------------
// bias2[h][m][n] = pos-bias for (q-row n, k-col m). Coalesced writes along n.
__global__ __launch_bounds__(256) void bias2_build_kernel(
    const bf16* __restrict__ posTg, bf16* __restrict__ bias2)
{
    int idx = blockIdx.x * 256 + threadIdx.x;   // 12*512*512 exact grid
    int h = idx >> 18;
    int m = (idx >> 9) & 511;
    int n = idx & 511;
    int dh = (n >> 6) - (m >> 6) + 7;
    int dw = ((n >> 3) & 7) - ((m >> 3) & 7) + 7;
    int dd = (n & 7) - (m & 7) + 7;
    bias2[idx] = posTg[h * LPAD + dh * 225 + dw * 15 + dd];
}

// ---------------------------------------------------------------------------
// mt[g][m][n] = (bf16)mask[g][n][m]; skipped entirely if mask is all-zero.
__global__ __launch_bounds__(256) void mt_build_kernel(
    const float* __restrict__ mask, bf16* __restrict__ mt,
    const int* __restrict__ flag)
{
    if (*flag == 0) return;
    __shared__ float tile[64][65];
    const int bx = blockIdx.x;           // g*64 + tm*8 + tn
    const int g  = bx >> 6;
    const int m0 = ((bx >> 3) & 7) * 64;
    const int n0 = (bx & 7) * 64;
    const int tid = threadIdx.x;
#pragma unroll
    for (int k = 0; k < 16; k++) {
        int lin = tid + k * 256;
        int r = lin >> 6, c = lin & 63;
        tile[r][c] = mask[((size_t)g * NTOK + n0 + r) * NTOK + m0 + c];
    }
    __syncthreads();
#pragma unroll
    for (int k = 0; k < 16; k++) {
        int lin = tid + k * 256;
        int mr = lin >> 6, nc = lin & 63;
        mt[((size_t)g * NTOK + m0 + mr) * NTOK + n0 + nc] = (bf16)tile[nc][mr];
    }
}

// ---------------------------------------------------------------------------
// GEMM: C[M][N] = A[M][K] @ Bt[N][K]^T + bias. 128x128 tile, BK=64.
// MODE 0: A = fp32 x, scatter bf16 into Q/K/V; Q prescaled by SM_SCALE.
// MODE 1: A = bf16 internal, write fp32 row-major to Of.
template <int MODE>
__global__ __launch_bounds__(256) void gemm_bt(
    const void* __restrict__ Av, const bf16* __restrict__ Bt,
    const float* __restrict__ bias,
    bf16* __restrict__ O0, bf16* __restrict__ O1, bf16* __restrict__ O2,
    float* __restrict__ Of, int K, int N)
{
    __shared__ __align__(16) bf16 lA[128 * 64];
    __shared__ __align__(16) bf16 lB[128 * 64];
    const int row0 = blockIdx.x * 128;
    const int col0 = blockIdx.y * 128;
    const int tid  = threadIdx.x;
    const int lane = tid & 63;
    const int wave = tid >> 6;
    const int r0   = (wave >> 1) * 64;
    const int c0   = (wave & 1) * 64;
    const int lrow = lane & 15;
    const int lch  = lane >> 4;

    f32x4 acc[4][4];
    const f32x4 zero4 = {0.f, 0.f, 0.f, 0.f};
#pragma unroll
    for (int i = 0; i < 4; i++)
#pragma unroll
        for (int j = 0; j < 4; j++) acc[i][j] = zero4;

    for (int kt = 0; kt < K; kt += 64) {
        __syncthreads();
#pragma unroll
        for (int it = 0; it < 4; it++) {
            const int c  = tid + it * 256;
            const int rr = c >> 3;
            const int cc = (c & 7) * 8;
            const size_t aoff = (size_t)(row0 + rr) * K + kt + cc;
            if (MODE == 0) {
                const float* Af = (const float*)Av + aoff;
                float4 f0 = *(const float4*)(Af);
                float4 f1 = *(const float4*)(Af + 4);
                bf16x8 v;
                v[0] = (bf16)f0.x; v[1] = (bf16)f0.y; v[2] = (bf16)f0.z; v[3] = (bf16)f0.w;
                v[4] = (bf16)f1.x; v[5] = (bf16)f1.y; v[6] = (bf16)f1.z; v[7] = (bf16)f1.w;
                *(bf16x8*)(lA + c * 8) = v;
            } else {
                *(uint4*)(lA + c * 8) = *(const uint4*)((const bf16*)Av + aoff);
            }
            *(uint4*)(lB + c * 8) = *(const uint4*)(Bt + (size_t)(col0 + rr) * K + kt + cc);
        }
        __syncthreads();
#pragma unroll
        for (int kk = 0; kk < 64; kk += 32) {
            bf16x8 af[4], bfr[4];
#pragma unroll
            for (int i = 0; i < 4; i++)
                af[i] = *(const bf16x8*)(lA + (r0 + i * 16 + lrow) * 64 + kk + lch * 8);
#pragma unroll
            for (int j = 0; j < 4; j++)
                bfr[j] = *(const bf16x8*)(lB + (c0 + j * 16 + lrow) * 64 + kk + lch * 8);
#pragma unroll
            for (int i = 0; i < 4; i++)
#pragma unroll
                for (int j = 0; j < 4; j++)
                    acc[i][j] = __builtin_amdgcn_mfma_f32_16x16x32_bf16(af[i], bfr[j], acc[i][j], 0, 0, 0);
        }
    }

#pragma unroll
    for (int i = 0; i < 4; i++) {
#pragma unroll
        for (int j = 0; j < 4; j++) {
#pragma unroll
            for (int r = 0; r < 4; r++) {
                const int mrow = row0 + r0 + i * 16 + lch * 4 + r;
                const int ncol = col0 + c0 + j * 16 + lrow;
                const float v = acc[i][j][r] + bias[ncol];
                if (MODE == 0) {
                    const int t    = ncol >= 768 ? 2 : (ncol >= 384 ? 1 : 0);
                    const int rem2 = ncol - t * 384;
                    const int hh   = rem2 >> 5;
                    const int dd   = rem2 & 31;
                    const int bwin = mrow >> 9;
                    const int n    = mrow & 511;
                    bf16* dst = (t == 0) ? O0 : ((t == 1) ? O1 : O2);
                    const float vv = (t == 0) ? v * SM_SCALE : v;   // Q prescale
                    dst[(size_t)((bwin * HEADS + hh) * NTOK + n) * HD + dd] = (bf16)vv;
                } else {
                    Of[(size_t)mrow * N + ncol] = v;
                }
            }
        }
    }
}

// ---------------------------------------------------------------------------
// Flash attention, barrier-free main loop. Q pre-scaled. BIG=1: bias/mask via
// b64 table loads; BIG=0: posT slice in LDS + scalar fp32 mask loads.
template <int BIG>
__global__ __launch_bounds__(256) void attn_kernel(
    const bf16* __restrict__ Qg, const bf16* __restrict__ Kg,
    const bf16* __restrict__ Vg, const bf16* __restrict__ posTg,
    const float* __restrict__ maskg, const bf16* __restrict__ bias2,
    const bf16* __restrict__ mt, const int* __restrict__ mflag,
    bf16* __restrict__ Og)
{
    __shared__ __align__(16) bf16 lVt[32 * VSTR];       // full V^T, 33,280 B
    __shared__ __align__(16) bf16 lP[4 * 32 * PSTR];    // 64-m half, 18,432 B
    __shared__ __align__(16) bf16 lPos[BIG ? 16 : LPAD];

    const int idx = blockIdx.x;
    const int h   = idx >> 8;
    const int rem = idx & 255;
    const int b   = rem >> 2;
    const int qt  = rem & 3;
    const int g   = b & 7;
    const int tid = threadIdx.x;
    const int lane = tid & 63;
    const int wave = tid >> 6;
    const int lrow = lane & 15;
    const int lch  = lane >> 4;
    const int msk  = *mflag;

    const bf16* Qp = Qg + (size_t)(b * HEADS + h) * NTOK * HD;
    const bf16* Kp = Kg + (size_t)(b * HEADS + h) * NTOK * HD;
    const bf16* Vp = Vg + (size_t)(b * HEADS + h) * NTOK * HD;
    const float* Mp = maskg + (size_t)g * NTOK * NTOK;
    const bf16* B2p = bias2 + (size_t)h * NTOK * NTOK;
    const bf16* Mtp = mt + (size_t)g * NTOK * NTOK;

    // --- stage full V^T once (the only barrier in this kernel) ---
    for (int n = tid; n < NTOK; n += 256) {
        const bf16* vsrc = Vp + n * HD;
        bf16x8 v0 = *(const bf16x8*)(vsrc);
        bf16x8 v1 = *(const bf16x8*)(vsrc + 8);
        bf16x8 v2 = *(const bf16x8*)(vsrc + 16);
        bf16x8 v3 = *(const bf16x8*)(vsrc + 24);
#pragma unroll
        for (int c = 0; c < 8; c++) {
            lVt[(c)      * VSTR + n] = v0[c];
            lVt[(8 + c)  * VSTR + n] = v1[c];
            lVt[(16 + c) * VSTR + n] = v2[c];
            lVt[(24 + c) * VSTR + n] = v3[c];
        }
    }
    if (!BIG) {   // stage this head's posT slice (6784 B) into LDS
        const uint4* src = (const uint4*)(posTg + h * LPAD);
        for (int i = tid; i < LPAD * 2 / 16; i += 256)
            ((uint4*)lPos)[i] = src[i];
    }
    __syncthreads();

    const int qbase = qt * 128 + wave * 32;

    bf16x8 qf[2];
#pragma unroll
    for (int rt = 0; rt < 2; rt++)
        qf[rt] = *(const bf16x8*)(Qp + (qbase + rt * 16 + lrow) * HD + lch * 8);

    float m_i[2][4], l_i[2][4];
    f32x4 oacc[2][2];
    const f32x4 zero4 = {0.f, 0.f, 0.f, 0.f};
#pragma unroll
    for (int rt = 0; rt < 2; rt++) {
#pragma unroll
        for (int r = 0; r < 4; r++) { m_i[rt][r] = -30.0f; l_i[rt][r] = 0.f; }
        oacc[rt][0] = zero4;
        oacc[rt][1] = zero4;
    }

    bf16* myP = lP + wave * (32 * PSTR);

    for (int kt = 0; kt < 4; kt++) {
        // S = Q @ K^T (Q pre-scaled by SM_SCALE)
        f32x4 sf[2][8];
#pragma unroll
        for (int ct = 0; ct < 8; ct++) {
            bf16x8 kf = *(const bf16x8*)(Kp + (kt * 128 + ct * 16 + lrow) * HD + lch * 8);
#pragma unroll
            for (int rt = 0; rt < 2; rt++)
                sf[rt][ct] = __builtin_amdgcn_mfma_f32_16x16x32_bf16(qf[rt], kf, zero4, 0, 0, 0);
        }

        // + bias (+ mask if nonzero)
        if (BIG) {
            const int n_base = qbase + lch * 4;           // mult of 4 -> 8B aligned
#pragma unroll
            for (int ct = 0; ct < 8; ct++) {
                const int m = kt * 128 + ct * 16 + lrow;
                const size_t tb = (size_t)m * NTOK + n_base;
#pragma unroll
                for (int rt = 0; rt < 2; rt++) {
                    bf16x4 bv = *(const bf16x4*)(B2p + tb + rt * 16);
#pragma unroll
                    for (int r = 0; r < 4; r++)
                        sf[rt][ct][r] += (float)bv[r];
                }
                if (msk) {
#pragma unroll
                    for (int rt = 0; rt < 2; rt++) {
                        bf16x4 mv = *(const bf16x4*)(Mtp + tb + rt * 16);
#pragma unroll
                        for (int r = 0; r < 4; r++)
                            sf[rt][ct][r] += (float)mv[r];
                    }
                }
            }
        } else {
            const int mb = kt * 128 + lrow;
#pragma unroll
            for (int rt = 0; rt < 2; rt++) {
#pragma unroll
                for (int r = 0; r < 4; r++) {
                    const int row = qbase + rt * 16 + lch * 4 + r;
                    const int nh = row >> 6, nw = (row >> 3) & 7, nd = row & 7;
                    const float* mp = Mp + (size_t)row * NTOK + mb;
#pragma unroll
                    for (int ct = 0; ct < 8; ct++) {
                        const int m  = mb + ct * 16;
                        const int rpi = (nh - (m >> 6) + 7) * 225
                                      + (nw - ((m >> 3) & 7) + 7) * 15
                                      + (nd - (m & 7) + 7);
                        sf[rt][ct][r] += (float)lPos[rpi];
                        if (msk) sf[rt][ct][r] += mp[ct * 16];
                    }
                }
            }
        }

        // online softmax; p values left in sf
#pragma unroll
        for (int rt = 0; rt < 2; rt++) {
#pragma unroll
            for (int r = 0; r < 4; r++) {
                float mx = sf[rt][0][r];
#pragma unroll
                for (int ct = 1; ct < 8; ct++) mx = fmaxf(mx, sf[rt][ct][r]);
                mx = fmaxf(mx, __shfl_xor(mx, 1));
                mx = fmaxf(mx, __shfl_xor(mx, 2));
                mx = fmaxf(mx, __shfl_xor(mx, 4));
                mx = fmaxf(mx, __shfl_xor(mx, 8));
                const float mold  = m_i[rt][r];
                const float mnew  = fmaxf(mold, mx);
                const float alpha = __expf(mold - mnew);
                m_i[rt][r] = mnew;
                float ls = 0.f;
#pragma unroll
                for (int ct = 0; ct < 8; ct++) {
                    float p = __expf(sf[rt][ct][r] - mnew);
                    ls += p;
                    sf[rt][ct][r] = p;
                }
                ls += __shfl_xor(ls, 1);
                ls += __shfl_xor(ls, 2);
                ls += __shfl_xor(ls, 4);
                ls += __shfl_xor(ls, 8);
                l_i[rt][r] = l_i[rt][r] * alpha + ls;
                oacc[rt][0][r] *= alpha;
                oacc[rt][1][r] *= alpha;
            }
        }

        // P@V in two 64-m halves through wave-private LDS (no barrier:
        // same-wave ds ordering is enforced by compiler lgkmcnt)
#pragma unroll
        for (int hf = 0; hf < 2; hf++) {
#pragma unroll
            for (int rt = 0; rt < 2; rt++)
#pragma unroll
                for (int r = 0; r < 4; r++) {
                    const int prow = (rt * 16 + lch * 4 + r) * PSTR + lrow;
#pragma unroll
                    for (int c4 = 0; c4 < 4; c4++)
                        myP[prow + c4 * 16] = (bf16)sf[rt][hf * 4 + c4][r];
                }
#pragma unroll
            for (int k2 = 0; k2 < 2; k2++) {
                const int mofs = kt * 128 + hf * 64 + k2 * 32;
                bf16x8 bv[2];
#pragma unroll
                for (int ct = 0; ct < 2; ct++)
                    bv[ct] = *(const bf16x8*)(lVt + (ct * 16 + lrow) * VSTR + mofs + lch * 8);
#pragma unroll
                for (int rt = 0; rt < 2; rt++) {
                    bf16x8 ap = *(const bf16x8*)(myP + (rt * 16 + lrow) * PSTR + k2 * 32 + lch * 8);
#pragma unroll
                    for (int ct = 0; ct < 2; ct++)
                        oacc[rt][ct] = __builtin_amdgcn_mfma_f32_16x16x32_bf16(ap, bv[ct], oacc[rt][ct], 0, 0, 0);
                }
            }
        }
    }

#pragma unroll
    for (int rt = 0; rt < 2; rt++) {
#pragma unroll
        for (int r = 0; r < 4; r++) {
            const int n = qbase + rt * 16 + lch * 4 + r;
            const float inv = 1.f / fmaxf(l_i[rt][r], 1e-20f);
            bf16* orow = Og + (size_t)(b * NTOK + n) * DIMC + h * HD;
#pragma unroll
            for (int ct = 0; ct < 2; ct++)
                orow[ct * 16 + lrow] = (bf16)(oacc[rt][ct][r] * inv);
        }
    }
}

// ---------------------------------------------------------------------------
extern "C" void kernel_launch(void* const* d_in, const int* in_sizes, int n_in,
                              void* d_out, int out_size, void* d_ws, size_t ws_size,
                              hipStream_t stream)
{
    if (ws_size < WS_SMALL) return;
    const bool BIG = (ws_size >= WS_BIG);

    const float* x      = (const float*)d_in[0];
    const float* maskp  = (const float*)d_in[4];
    const float* qkv_w  = (const float*)d_in[5];
    const float* qkv_b  = (const float*)d_in[6];
    const float* proj_w = (const float*)d_in[7];
    const float* proj_b = (const float*)d_in[8];

    char* ws = (char*)d_ws;
    size_t off = 0;
    bf16* wsWqT  = (bf16*)(ws + off); off += SZ_WQT;
    bf16* wsWpT  = (bf16*)(ws + off); off += SZ_WPT;
    bf16* wsPosT = (bf16*)(ws + off); off += SZ_POST;
    int*  wsFlag = (int*)(ws + off);  off += SZ_FLAG;
    bf16* wsB2 = nullptr; bf16* wsMt = nullptr;
    if (BIG) {
        wsB2 = (bf16*)(ws + off); off += SZ_B2;
        wsMt = (bf16*)(ws + off); off += SZ_MT;
    } else {
        off = 1572864;   // round-4 proven layout
    }
    bf16* wsQ    = (bf16*)(ws + off); off += SZ_QKV;
    bf16* wsK    = (bf16*)(ws + off); off += SZ_QKV;
    bf16* wsV    = (bf16*)(ws + off); off += SZ_QKV;
    bf16* wsAttn = (bf16*)(ws + off);

    hipMemsetAsync(wsFlag, 0, 4, stream);
    mask_detect_kernel<<<256, 256, 0, stream>>>(maskp, wsFlag);

    transpose_kernel<<<(384 * 1152 + 255) / 256, 256, 0, stream>>>(qkv_w, wsWqT, 384, 1152);
    transpose_kernel<<<(384 * 384 + 255) / 256, 256, 0, stream>>>(proj_w, wsWpT, 384, 384);
    pos_mlp_kernel<<<(LTAB + 255) / 256, 256, 0, stream>>>(
        (const float*)d_in[9],  (const float*)d_in[10], (const float*)d_in[11],
        (const float*)d_in[12], (const float*)d_in[13], (const float*)d_in[14],
        (const float*)d_in[15], (const float*)d_in[16], (const float*)d_in[17],
        (const float*)d_in[18], (const float*)d_in[19], (const float*)d_in[20],
        (const float*)d_in[21], (const float*)d_in[22], wsPosT);

    if (BIG) {
        bias2_build_kernel<<<(HEADS * NTOK * NTOK) / 256, 256, 0, stream>>>(wsPosT, wsB2);
        mt_build_kernel<<<8 * 64, 256, 0, stream>>>(maskp, wsMt, wsFlag);
    }

    // QKV: [32768 x 384] @ [384 x 1152] -> scatter Q/K/V (Q pre-scaled)
    gemm_bt<0><<<dim3(256, 9), 256, 0, stream>>>(x, wsWqT, qkv_b, wsQ, wsK, wsV,
                                                 nullptr, 384, 1152);

    if (BIG)
        attn_kernel<1><<<HEADS * NWIN * 4, 256, 0, stream>>>(
            wsQ, wsK, wsV, wsPosT, maskp, wsB2, wsMt, wsFlag, wsAttn);
    else
        attn_kernel<0><<<HEADS * NWIN * 4, 256, 0, stream>>>(
            wsQ, wsK, wsV, wsPosT, maskp, wsB2, wsMt, wsFlag, wsAttn);

    // proj: [32768 x 384] @ [384 x 384] -> d_out (fp32)
    gemm_bt<1><<<dim3(256, 3), 256, 0, stream>>>(wsAttn, wsWpT, proj_b,
                                                 nullptr, nullptr, nullptr,
                                                 (float*)d_out, 384, 384);
}